// Round 1
// baseline (135.423 us; speedup 1.0000x reference)
//
#include <hip/hip_runtime.h>
#include <hip/hip_bf16.h>

#define N 8192
#define F 128

typedef __attribute__((ext_vector_type(4)))  float f32x4;
typedef __attribute__((ext_vector_type(16))) float f32x16;
typedef __attribute__((ext_vector_type(8)))  short short8;

static __device__ __forceinline__ unsigned short f2bf(float x) {
  union { float f; unsigned u; } v; v.f = x;
  unsigned r = v.u + 0x7FFF + ((v.u >> 16) & 1);   // RNE (inputs are finite, positive)
  return (unsigned short)(r >> 16);
}

// ---------------------------------------------------------------------------
// Kernel A: Wh = h @ W (fp32), fused c[i] = Wh[i].a2 + p.a3, d[i] = Wh[i].a1 - p.a3,
// and WhT (bf16, [128][8192]) for the flash kernel's B operand.
// 256 blocks x 256 threads, 32 rows/block. W staged fp32 in 64 KiB LDS.
// ---------------------------------------------------------------------------
__global__ __launch_bounds__(256) void k_gemm_cd(
    const float* __restrict__ h, const float* __restrict__ pos,
    const float* __restrict__ W, const float* __restrict__ a,
    unsigned short* __restrict__ WhT, float* __restrict__ cArr,
    float* __restrict__ dArr)
{
  __shared__ float Ws[128 * 128];          // 64 KiB, reused as transpose buffer after
  const int tid = threadIdx.x;
  const int r0  = blockIdx.x * 32;

  // stage W (coalesced float4)
  {
    f32x4* Ws4 = (f32x4*)Ws;
    const f32x4* Wg4 = (const f32x4*)W;
#pragma unroll
    for (int q = 0; q < 16; ++q) Ws4[q * 256 + tid] = Wg4[q * 256 + tid];
  }
  __syncthreads();

  const int rg  = tid >> 4;    // 0..15 -> rows rg*2, rg*2+1
  const int c16 = tid & 15;    // cols c16*8 .. c16*8+7

  f32x4 acc[2][2];
#pragma unroll
  for (int rr = 0; rr < 2; ++rr)
#pragma unroll
    for (int q = 0; q < 2; ++q)
#pragma unroll
      for (int i = 0; i < 4; ++i) acc[rr][q][i] = 0.0f;

  const f32x4* h40 = (const f32x4*)(h + (size_t)(r0 + rg * 2) * 128);
  const f32x4* h41 = (const f32x4*)(h + (size_t)(r0 + rg * 2 + 1) * 128);
  const f32x4* Ws4 = (const f32x4*)Ws;

#pragma unroll 4
  for (int k4 = 0; k4 < 32; ++k4) {
    f32x4 hv0 = h40[k4];
    f32x4 hv1 = h41[k4];
#pragma unroll
    for (int e = 0; e < 4; ++e) {
      const int k = k4 * 4 + e;
      f32x4 w0 = Ws4[k * 32 + c16 * 2];
      f32x4 w1 = Ws4[k * 32 + c16 * 2 + 1];
      acc[0][0] += hv0[e] * w0; acc[0][1] += hv0[e] * w1;
      acc[1][0] += hv1[e] * w0; acc[1][1] += hv1[e] * w1;
    }
  }

  // fused row dots: s1 = Wh.a1 (for d), s2 = Wh.a2 (for c)
  f32x4 a10 = *(const f32x4*)(a + c16 * 8);
  f32x4 a11 = *(const f32x4*)(a + c16 * 8 + 4);
  f32x4 a20 = *(const f32x4*)(a + 128 + c16 * 8);
  f32x4 a21 = *(const f32x4*)(a + 128 + c16 * 8 + 4);
#pragma unroll
  for (int rr = 0; rr < 2; ++rr) {
    f32x4 t1 = acc[rr][0] * a10 + acc[rr][1] * a11;
    f32x4 t2 = acc[rr][0] * a20 + acc[rr][1] * a21;
    float s1 = t1[0] + t1[1] + t1[2] + t1[3];
    float s2 = t2[0] + t2[1] + t2[2] + t2[3];
#pragma unroll
    for (int m = 1; m < 16; m <<= 1) {
      s1 += __shfl_xor(s1, m);
      s2 += __shfl_xor(s2, m);
    }
    if (c16 == 0) {
      const int row = r0 + rg * 2 + rr;
      float pa = pos[row * 3 + 0] * a[256] + pos[row * 3 + 1] * a[257] +
                 pos[row * 3 + 2] * a[258];
      cArr[row] = s2 + pa;     // i-side
      dArr[row] = s1 - pa;     // j-side
    }
  }

  // transpose via LDS (reuse Ws), write bf16 WhT[col][row]
  __syncthreads();
  float* tmp = Ws;             // [32][132] padded
  {
    const int base = (rg * 2) * 132 + c16 * 8;
    *(f32x4*)&tmp[base]           = acc[0][0];
    *(f32x4*)&tmp[base + 4]       = acc[0][1];
    *(f32x4*)&tmp[base + 132]     = acc[1][0];
    *(f32x4*)&tmp[base + 132 + 4] = acc[1][1];
  }
  __syncthreads();
  {
    const int col = tid >> 1;          // 0..127
    const int rh  = tid & 1;           // 0..1 -> local rows rh*16..rh*16+15
    short8 o0, o1;
#pragma unroll
    for (int rr = 0; rr < 8; ++rr)
      o0[rr] = (short)f2bf(tmp[(rh * 16 + rr) * 132 + col]);
#pragma unroll
    for (int rr = 0; rr < 8; ++rr)
      o1[rr] = (short)f2bf(tmp[(rh * 16 + 8 + rr) * 132 + col]);
    unsigned short* dst = WhT + (size_t)col * N + r0 + rh * 16;
    *(short8*)dst = o0;
    *(short8*)(dst + 8) = o1;
  }
}

// ---------------------------------------------------------------------------
// Kernel B: flash-style attention (no max subtraction needed -- scores bounded).
// Grid 256: bid = (rowblock<<1) | jchunk.  64 rows x 4096 j per block.
// 4 waves: (w&1) selects 32-row tile, (w>>1) selects 2048-j half.
// A-frag = P computed in-register; B-frag = contiguous short8 from WhT.
// ---------------------------------------------------------------------------
__global__ __launch_bounds__(256) void k_flash(
    const unsigned short* __restrict__ WhT, const float* __restrict__ cArr,
    const float* __restrict__ dArr, float* __restrict__ pnum,
    float* __restrict__ pden)
{
  __shared__ __align__(16) float dS[4096];
  __shared__ float red[64 * 128];
  __shared__ float denred[64];

  const int tid = threadIdx.x;
  const int bid = blockIdx.x;
  const int jc  = bid & 1;
  const int r0  = (bid >> 1) * 64;

  // stage this block's d-slice (16 KiB)
  {
    const f32x4* s4 = (const f32x4*)(dArr + jc * 4096);
    f32x4* t4 = (f32x4*)dS;
#pragma unroll
    for (int q = 0; q < 4; ++q) t4[q * 256 + tid] = s4[q * 256 + tid];
  }
  __syncthreads();

  const int w  = tid >> 6;
  const int l  = tid & 63;
  const int cl = l & 31;
  const int rowl = 32 * (w & 1) + cl;        // A-frag row = lane&31
  const int jw = (w >> 1) * 2048;
  const int kb = (l >> 5) * 8;               // A/B-frag k base

  const float L2E = 1.44269504f;
  const float ciL = cArr[r0 + rowl] * L2E;

  f32x16 acc0, acc1, acc2, acc3;
#pragma unroll
  for (int i = 0; i < 16; ++i) { acc0[i] = 0; acc1[i] = 0; acc2[i] = 0; acc3[i] = 0; }
  float den = 0.0f;

  const unsigned short* v0 = WhT + (size_t)(cl +  0) * N + jc * 4096;
  const unsigned short* v1 = WhT + (size_t)(cl + 32) * N + jc * 4096;
  const unsigned short* v2 = WhT + (size_t)(cl + 64) * N + jc * 4096;
  const unsigned short* v3 = WhT + (size_t)(cl + 96) * N + jc * 4096;

  for (int kk = 0; kk < 128; ++kk) {
    const int jo = jw + kk * 16 + kb;
    f32x4 dj0 = *(const f32x4*)&dS[jo];
    f32x4 dj1 = *(const f32x4*)&dS[jo + 4];
    float p[8];
#pragma unroll
    for (int e = 0; e < 8; ++e) {
      float dj = (e < 4) ? dj0[e] : dj1[e - 4];
      float u = __builtin_fmaf(dj, L2E, ciL);  // (c_i + d_j) * log2(e)
      u = fmaxf(u, 0.2f * u);                  // leaky_relu in log2 domain
      float pv = __builtin_amdgcn_exp2f(u);
      den += pv;
      p[e] = pv;
    }
    short8 af;
#pragma unroll
    for (int e = 0; e < 8; ++e) af[e] = (short)f2bf(p[e]);
    short8 b0 = *(const short8*)(v0 + jo);
    short8 b1 = *(const short8*)(v1 + jo);
    short8 b2 = *(const short8*)(v2 + jo);
    short8 b3 = *(const short8*)(v3 + jo);
    acc0 = __builtin_amdgcn_mfma_f32_32x32x16_bf16(af, b0, acc0, 0, 0, 0);
    acc1 = __builtin_amdgcn_mfma_f32_32x32x16_bf16(af, b1, acc1, 0, 0, 0);
    acc2 = __builtin_amdgcn_mfma_f32_32x32x16_bf16(af, b2, acc2, 0, 0, 0);
    acc3 = __builtin_amdgcn_mfma_f32_32x32x16_bf16(af, b3, acc3, 0, 0, 0);
  }

  // full row denominator: lanes l and l+32 hold the two k-halves of the same row
  den += __shfl_xor(den, 32);

  // cross-wave reduce (j-halves) through LDS
  const int rtb = 32 * (w & 1);
  const int rhi = 4 * (l >> 5);
  if (w < 2) {
#pragma unroll
    for (int reg = 0; reg < 16; ++reg) {
      const int rt = (reg & 3) + 8 * (reg >> 2) + rhi;
      red[(rtb + rt) * 128 +  0 + cl] = acc0[reg];
      red[(rtb + rt) * 128 + 32 + cl] = acc1[reg];
      red[(rtb + rt) * 128 + 64 + cl] = acc2[reg];
      red[(rtb + rt) * 128 + 96 + cl] = acc3[reg];
    }
    if (l < 32) denred[rtb + l] = den;
  }
  __syncthreads();
  if (w >= 2) {
#pragma unroll
    for (int reg = 0; reg < 16; ++reg) {
      const int rt = (reg & 3) + 8 * (reg >> 2) + rhi;
      red[(rtb + rt) * 128 +  0 + cl] += acc0[reg];
      red[(rtb + rt) * 128 + 32 + cl] += acc1[reg];
      red[(rtb + rt) * 128 + 64 + cl] += acc2[reg];
      red[(rtb + rt) * 128 + 96 + cl] += acc3[reg];
    }
    if (l < 32) denred[rtb + l] += den;
  }
  __syncthreads();

  // write partials
  {
    f32x4* pn4 = (f32x4*)(pnum + (size_t)jc * N * F + (size_t)r0 * 128);
    const f32x4* r4 = (const f32x4*)red;
#pragma unroll
    for (int q = 0; q < 8; ++q) pn4[q * 256 + tid] = r4[q * 256 + tid];
    if (tid < 64) pden[jc * N + r0 + tid] = denred[tid];
  }
}

// ---------------------------------------------------------------------------
// Kernel C: combine the 2 j-chunk partials, normalize, ELU, store fp32.
// ---------------------------------------------------------------------------
__global__ __launch_bounds__(256) void k_final(
    const float* __restrict__ pnum, const float* __restrict__ pden,
    float* __restrict__ out)
{
  const int g = blockIdx.x * 256 + threadIdx.x;       // float4 index
  f32x4 n = ((const f32x4*)pnum)[g] +
            ((const f32x4*)(pnum + (size_t)N * F))[g];
  const int row = g >> 5;
  const float dd = pden[row] + pden[N + row];
  f32x4 r = n * (1.0f / dd);
#pragma unroll
  for (int i = 0; i < 4; ++i) {
    float x = r[i];
    r[i] = x > 0.0f ? x : (__builtin_amdgcn_exp2f(x * 1.44269504f) - 1.0f);
  }
  ((f32x4*)out)[g] = r;
}

extern "C" void kernel_launch(void* const* d_in, const int* in_sizes, int n_in,
                              void* d_out, int out_size, void* d_ws, size_t ws_size,
                              hipStream_t stream)
{
  const float* h   = (const float*)d_in[0];
  const float* pos = (const float*)d_in[1];
  const float* W   = (const float*)d_in[2];
  const float* a   = (const float*)d_in[3];
  float* out = (float*)d_out;

  char* ws = (char*)d_ws;
  unsigned short* WhT = (unsigned short*)ws;                 // 2 MiB  bf16 [128][8192]
  float* cArr = (float*)(ws + (size_t)2 * 1024 * 1024);      // 32 KiB
  float* dArr = cArr + N;                                    // 32 KiB
  float* pden = dArr + N;                                    // 2*N floats
  float* pnum = pden + 2 * N;                                // 2*N*F floats (8 MiB)

  hipLaunchKernelGGL(k_gemm_cd, dim3(256), dim3(256), 0, stream,
                     h, pos, W, a, WhT, cArr, dArr);
  hipLaunchKernelGGL(k_flash, dim3(256), dim3(256), 0, stream,
                     WhT, cArr, dArr, pnum, pden);
  hipLaunchKernelGGL(k_final, dim3((N * F / 4) / 256), dim3(256), 0, stream,
                     pnum, pden, out);
}